// Round 7
// baseline (280.018 us; speedup 1.0000x reference)
//
#include <hip/hip_runtime.h>

// Problem constants (fixed by the reference: B=16, D=256, K=64, H=W=96)
#define NDIM  256
#define NK    64
#define NPIX  9216
#define NB    16
#define TN    64           // pixels per tile
#define NTILE 144          // NPIX / TN
#define NW    48           // writer blocks per batch
#define TPB   3            // tiles per block = 144/NW
#define GRID  (NB*NW)      // 768 = 3 blocks/CU resident, no tail

typedef _Float16 half2_t __attribute__((ext_vector_type(2)));
typedef _Float16 half8_t __attribute__((ext_vector_type(8)));
typedef float    f32x4  __attribute__((ext_vector_type(4)));

__device__ __forceinline__ float fdot2(half2_t a, half2_t b, float c) {
  return __builtin_amdgcn_fdot2(a, b, c, false);
}

// ws layout (float offsets):
//   ChH   f16[NK][NDIM]           8192 f
//   c2    [NK]                      64 f
//   asum  [NB][NK]                1024 f
//   Apart [GRID][NK]             49152 f
//   x2    [NB][NPIX]            147456 f
//   Xh    f16[NB][NTILE][32*64*8]       75.5 MB
//   EpartH f16[GRID][NK*NDIM]           25.2 MB   | E_acc f32 (fallback)
#define OFF_CH     0
#define OFF_C2     (NK * NDIM / 2)
#define OFF_ASUM   (OFF_C2 + NK)
#define OFF_APART  (OFF_ASUM + NB * NK)
#define OFF_X2     (OFF_APART + GRID * NK)
#define OFF_XH     (OFF_X2 + NB * NPIX)
#define XH_F       ((size_t)NB * NTILE * 32 * 64 * 8 / 2)   // halves->floats
#define OFF_EPART  ((size_t)OFF_XH + XH_F)
#define WS_NEED    (OFF_EPART * 4 + (size_t)GRID * NK * NDIM * 2)

// ---- c2[k] + f16 codeword pack ----
__global__ void c2ch_kernel(const float* __restrict__ Cw, float* __restrict__ c2,
                            _Float16* __restrict__ ChH) {
  const int k = blockIdx.x, t = threadIdx.x;
  const float4 v = *(const float4*)(Cw + k * NDIM + 4 * t);
  half2_t h0; h0.x = (_Float16)v.x; h0.y = (_Float16)v.y;
  half2_t h1; h1.x = (_Float16)v.z; h1.y = (_Float16)v.w;
  *(half2_t*)&ChH[k * NDIM + 4 * t]     = h0;
  *(half2_t*)&ChH[k * NDIM + 4 * t + 2] = h1;
  float s = v.x*v.x + v.y*v.y + v.z*v.z + v.w*v.w;
#pragma unroll
  for (int o = 32; o; o >>= 1) s += __shfl_down(s, o);
  if (t == 0) c2[k] = s;
}

// ---- kernel A: X fp32 -> pre-blocked f16 tiles + per-pixel x^2 ----
// Pure streaming (151 MB in, 76 MB out). Tile image = Xh[tile][dchunk][p][8],
// i.e. exactly the LDS layout encode_b consumes -> its staging is a flat copy.
__global__ __launch_bounds__(256) void convert_x(
    const float* __restrict__ X, _Float16* __restrict__ Xh,
    float* __restrict__ x2g) {
  __shared__ float red[4][TN];
  const int tid = threadIdx.x;
  const int w = tid >> 6, lane = tid & 63;
  const int b = blockIdx.x / NTILE, tile = blockIdx.x % NTILE;
  const int n0 = tile * TN;
  const float* Xg = X + (size_t)b * NDIM * NPIX + (size_t)(w * 64) * NPIX + n0 + lane;
  _Float16* dst = Xh + (size_t)(b * NTILE + tile) * (32 * 64 * 8);
  float xsq = 0.f;
#pragma unroll
  for (int g = 0; g < 8; ++g) {
    float v[8];
#pragma unroll
    for (int i = 0; i < 8; ++i) v[i] = Xg[(size_t)(g * 8 + i) * NPIX];
    half8_t hv;
#pragma unroll
    for (int i = 0; i < 8; ++i) { hv[i] = (_Float16)v[i]; xsq += v[i] * v[i]; }
    *(half8_t*)&dst[((w * 8 + g) * 64 + lane) * 8] = hv;   // coalesced b128
  }
  red[w][lane] = xsq;
  __syncthreads();
  if (tid < TN)
    x2g[b * NPIX + n0 + tid] = red[0][tid] + red[1][tid] + red[2][tid] + red[3][tid];
}

// ---- kernel B: lean fused MFMA (pre-converted f16 input) ----
// Staging = 8 b128 loads + 8 b128 LDS stores per thread (flat copy; R6's 64
// strided dwords + f32->f16 cvt are gone -> critical path shrinks, VGPRs
// freed). x^2 precomputed (red2 gone); asum folded into phase-2 registers.
// LDS 44 KB -> 3 blocks/CU; grid 768 = exactly full residency.
__global__ __launch_bounds__(256, 2) void encode_b(
    const _Float16* __restrict__ Xh, const float* __restrict__ x2g,
    const _Float16* __restrict__ ChH, const float* __restrict__ scale,
    const float* __restrict__ c2, void* __restrict__ Eout,
    float* __restrict__ Aout, int mode)
{
  __shared__ __align__(16) char smem[44032];
  _Float16* XbS = (_Float16*)smem;                         // [32*64*8], 32 KB
  _Float16 (*Al)[72] = (_Float16(*)[72])(smem + 32768);    // [64][72], 9.2 KB
  float* redM = (float*)(smem + 32768 + 9216);             // [4][64]
  float* redS = (float*)(smem + 32768 + 9216 + 1024);      // [4][64]

  const int tid  = threadIdx.x;
  const int w    = __builtin_amdgcn_readfirstlane(tid >> 6);
  const int lane = tid & 63;
  const int m    = lane & 15, quad = lane >> 4;
  const int b    = blockIdx.x / NW;
  const int wid  = blockIdx.x % NW;
  const int kbase = w * 16;

  // phase-1 A-frags (codewords): tile-invariant, 16 VGPRs
  half8_t af1[8];
#pragma unroll
  for (int ks = 0; ks < 8; ++ks)
    af1[ks] = *(const half8_t*)(ChH + (kbase + m) * NDIM + ks * 32 + quad * 8);

  const float4 scv = *(const float4*)(scale + kbase + quad * 4);
  const float4 c2v = *(const float4*)(c2 + kbase + quad * 4);
  const float sc[4] = {scv.x, scv.y, scv.z, scv.w};
  const float sq[4] = {scv.x * c2v.x, scv.y * c2v.y, scv.z * c2v.z, scv.w * c2v.w};

  f32x4 acc_e[4][4];
#pragma unroll
  for (int i = 0; i < 4; ++i)
#pragma unroll
    for (int j = 0; j < 4; ++j)
      acc_e[i][j] = (f32x4){0.f, 0.f, 0.f, 0.f};
  float asum_r[4] = {0.f, 0.f, 0.f, 0.f};   // per-lane asum partials (fp32)

  for (int tt = 0; tt < TPB; ++tt) {
    const int tile = wid + tt * NW;
    const _Float16* src = Xh + (size_t)(b * NTILE + tile) * (32 * 64 * 8);
    __syncthreads();                   // B1: prev tile's phase-3 reads done

    // ---- stage: flat 32 KB copy, 8 x (b128 load + b128 LDS store) ----
    half8_t stg[8];
#pragma unroll
    for (int r = 0; r < 8; ++r)
      stg[r] = *(const half8_t*)&src[(size_t)(tid + r * 256) * 8];
    // x^2 for this wave's softmax pixels (independent of LDS)
    float x2v[4];
#pragma unroll
    for (int nt = 0; nt < 4; ++nt)
      x2v[nt] = x2g[b * NPIX + tile * TN + nt * 16 + m];
#pragma unroll
    for (int r = 0; r < 8; ++r)
      *(half8_t*)&XbS[(tid + r * 256) * 8] = stg[r];
    __syncthreads();                   // B2: XbS visible

    // ---- phase 1 MFMA: S^T[k 16][p 64] per wave ----
    f32x4 accs[4];
#pragma unroll
    for (int nt = 0; nt < 4; ++nt) accs[nt] = (f32x4){0.f, 0.f, 0.f, 0.f};
#pragma unroll
    for (int ks = 0; ks < 8; ++ks) {
#pragma unroll
      for (int nt = 0; nt < 4; ++nt) {
        const half8_t bf = *(const half8_t*)&XbS[((ks * 4 + quad) * 64 + nt * 16 + m) * 8];
        accs[nt] = __builtin_amdgcn_mfma_f32_16x16x32_f16(af1[ks], bf, accs[nt], 0, 0, 0);
      }
    }

    // ---- phase 2: softmax over k; in-wave shfl + one LDS exchange ----
    float e[4][4], mw[4];
#pragma unroll
    for (int nt = 0; nt < 4; ++nt) {
      const int p = nt * 16 + m;
      float L[4];
      float mx = -3.0e38f;
#pragma unroll
      for (int r = 0; r < 4; ++r) {
        L[r] = sc[r] * x2v[nt] - 2.f * sc[r] * accs[nt][r] + sq[r];
        mx = fmaxf(mx, L[r]);
      }
      mx = fmaxf(mx, __shfl_xor(mx, 16));
      mx = fmaxf(mx, __shfl_xor(mx, 32));
      float s = 0.f;
#pragma unroll
      for (int r = 0; r < 4; ++r) { e[nt][r] = __expf(L[r] - mx); s += e[nt][r]; }
      s += __shfl_xor(s, 16);
      s += __shfl_xor(s, 32);
      mw[nt] = mx;
      if (lane < 16) { redM[w * 64 + p] = mx; redS[w * 64 + p] = s; }
    }
    __syncthreads();                   // B3: cross-wave max/sum exchange
#pragma unroll
    for (int nt = 0; nt < 4; ++nt) {
      const int p = nt * 16 + m;
      const float M = fmaxf(fmaxf(redM[0 * 64 + p], redM[1 * 64 + p]),
                            fmaxf(redM[2 * 64 + p], redM[3 * 64 + p]));
      const float T = redS[0 * 64 + p] * __expf(redM[0 * 64 + p] - M)
                    + redS[1 * 64 + p] * __expf(redM[1 * 64 + p] - M)
                    + redS[2 * 64 + p] * __expf(redM[2 * 64 + p] - M)
                    + redS[3 * 64 + p] * __expf(redM[3 * 64 + p] - M);
      const float norm = __expf(mw[nt] - M) / T;
#pragma unroll
      for (int r = 0; r < 4; ++r) {
        const float a = e[nt][r] * norm;
        Al[kbase + quad * 4 + r][p] = (_Float16)a;
        asum_r[r] += a;                // fp32 asum, folded here
      }
    }
    __syncthreads();                   // B4: Al visible

    // ---- phase 3 MFMA: E^T[d 64][k 64] per wave ----
#pragma unroll
    for (int ks = 0; ks < 2; ++ks) {
      half8_t ba[4];
#pragma unroll
      for (int kt = 0; kt < 4; ++kt)
        ba[kt] = *(const half8_t*)&Al[kt * 16 + m][ks * 32 + quad * 8];
#pragma unroll
      for (int dt = 0; dt < 4; ++dt) {
        const int c = w * 8 + dt * 2 + (m >> 3);
        const int dlow = m & 7;
        half8_t xa;                    // 8 u16 gathers (~2-way, free)
#pragma unroll
        for (int j = 0; j < 8; ++j)
          xa[j] = XbS[((c * 64 + ks * 32 + quad * 8 + j)) * 8 + dlow];
#pragma unroll
        for (int kt = 0; kt < 4; ++kt)
          acc_e[dt][kt] = __builtin_amdgcn_mfma_f32_16x16x32_f16(xa, ba[kt], acc_e[dt][kt], 0, 0, 0);
      }
    }
  }

  // ---- epilogue ----
  __syncthreads();                     // XbS/Al dead -> alias as Et[64][264]
  _Float16* Et = (_Float16*)smem;
#pragma unroll
  for (int dt = 0; dt < 4; ++dt)
#pragma unroll
    for (int kt = 0; kt < 4; ++kt)
#pragma unroll
      for (int r = 0; r < 4; ++r) {
        const int k = kt * 16 + m;               // C/D: col=lane&15 -> k
        const int d = w * 64 + dt * 16 + quad * 4 + r;
        Et[k * 264 + d] = (_Float16)acc_e[dt][kt][r];
      }
  // asum: reduce over the 16 m-lanes (same quad stays)
#pragma unroll
  for (int r = 0; r < 4; ++r) {
#pragma unroll
    for (int off = 1; off < 16; off <<= 1)
      asum_r[r] += __shfl_xor(asum_r[r], off);
  }
  __syncthreads();
  const int ko = tid >> 2, cq = tid & 3;
  if (mode) {
    _Float16* Ebk = (_Float16*)Eout + (size_t)blockIdx.x * (NK * NDIM);
#pragma unroll
    for (int g = 0; g < 8; ++g)
      *(half8_t*)&Ebk[ko * NDIM + cq * 64 + g * 8] =
          *(const half8_t*)&Et[ko * 264 + cq * 64 + g * 8];
    if (m == 0)
#pragma unroll
      for (int r = 0; r < 4; ++r)
        Aout[blockIdx.x * NK + kbase + quad * 4 + r] = asum_r[r];
  } else {
    float* Ebk = (float*)Eout + (size_t)b * (NK * NDIM);
#pragma unroll
    for (int g = 0; g < 64; ++g)
      atomicAdd(&Ebk[ko * NDIM + cq * 64 + g], (float)Et[ko * 264 + cq * 64 + g]);
    if (m == 0)
#pragma unroll
      for (int r = 0; r < 4; ++r)
        atomicAdd(&Aout[b * NK + kbase + quad * 4 + r], asum_r[r]);
  }
}

// ---- asum[b][k] = sum_w Apart[(b*NW+w)][k] ----
__global__ void asum_reduce_kernel(const float* __restrict__ Apart,
                                   float* __restrict__ asum) {
  const int i = blockIdx.x * 256 + threadIdx.x;
  const int bb = i >> 6, k = i & 63;
  float s = 0.f;
#pragma unroll 8
  for (int w = 0; w < NW; ++w) s += Apart[(bb * NW + w) * NK + k];
  asum[i] = s;
}

// ---- out = sum_w Epart(f16) - asum*C (b128 loads) ----
__global__ void finalize_partials(const _Float16* __restrict__ EpartH,
                                  const float* __restrict__ asum,
                                  const float* __restrict__ Cw,
                                  float* __restrict__ out) {
  const int g = blockIdx.x * 256 + threadIdx.x;
  const int i0 = g * 8;
  const int bb = i0 >> 14;
  const int o  = i0 & 16383;
  const int k  = o >> 8, d = i0 & 255;
  float s[8];
#pragma unroll
  for (int j = 0; j < 8; ++j) s[j] = 0.f;
  const _Float16* base = EpartH + (((size_t)bb * NW) << 14) + o;
#pragma unroll 4
  for (int w = 0; w < NW; ++w) {
    const half8_t v = *(const half8_t*)(base + ((size_t)w << 14));
#pragma unroll
    for (int j = 0; j < 8; ++j) s[j] += (float)v[j];
  }
  const float a = asum[bb * NK + k];
  const float4 c0 = *(const float4*)(Cw + k * NDIM + d);
  const float4 c1 = *(const float4*)(Cw + k * NDIM + d + 4);
  float4 r0, r1;
  r0.x = s[0] - a * c0.x; r0.y = s[1] - a * c0.y;
  r0.z = s[2] - a * c0.z; r0.w = s[3] - a * c0.w;
  r1.x = s[4] - a * c1.x; r1.y = s[5] - a * c1.y;
  r1.z = s[6] - a * c1.z; r1.w = s[7] - a * c1.w;
  *(float4*)(out + i0)     = r0;
  *(float4*)(out + i0 + 4) = r1;
}

// ---- out = E_acc - asum*C (atomic-fallback mode) ----
__global__ void finalize_atomic(const float* __restrict__ E_acc,
                                const float* __restrict__ asum,
                                const float* __restrict__ Cw,
                                float* __restrict__ out) {
  const int i = blockIdx.x * 256 + threadIdx.x;
  const int d = i & 255;
  const int k = (i >> 8) & 63;
  const int bb = i >> 14;
  out[i] = E_acc[i] - asum[bb * NK + k] * Cw[k * NDIM + d];
}

extern "C" void kernel_launch(void* const* d_in, const int* in_sizes, int n_in,
                              void* d_out, int out_size, void* d_ws, size_t ws_size,
                              hipStream_t stream) {
  const float* X     = (const float*)d_in[0];
  const float* Cw    = (const float*)d_in[1];
  const float* scale = (const float*)d_in[2];
  float* out = (float*)d_out;

  float* wsf = (float*)d_ws;
  _Float16* ChH = (_Float16*)(wsf + OFF_CH);
  float* c2     = wsf + OFF_C2;
  float* asum   = wsf + OFF_ASUM;
  float* Apart  = wsf + OFF_APART;
  float* x2g    = wsf + OFF_X2;
  _Float16* Xh  = (_Float16*)(wsf + OFF_XH);

  c2ch_kernel<<<NK, 64, 0, stream>>>(Cw, c2, ChH);
  convert_x<<<NB * NTILE, 256, 0, stream>>>(X, Xh, x2g);
  if (ws_size >= WS_NEED) {
    _Float16* EpartH = (_Float16*)(wsf + OFF_EPART);
    encode_b<<<GRID, 256, 0, stream>>>(Xh, x2g, ChH, scale, c2, EpartH, Apart, 1);
    asum_reduce_kernel<<<4, 256, 0, stream>>>(Apart, asum);
    finalize_partials<<<(NB*NK*NDIM)/(256*8), 256, 0, stream>>>(EpartH, asum, Cw, out);
  } else {
    float* E_acc = (float*)(wsf + OFF_EPART);    // fp32 atomic accumulator
    hipMemsetAsync(asum, 0, (size_t)(NB*NK) * sizeof(float), stream);
    hipMemsetAsync(E_acc, 0, (size_t)(NB*NK*NDIM) * sizeof(float), stream);
    encode_b<<<GRID, 256, 0, stream>>>(Xh, x2g, ChH, scale, c2, E_acc, asum, 0);
    finalize_atomic<<<(NB*NK*NDIM)/256, 256, 0, stream>>>(E_acc, asum, Cw, out);
  }
}